// Round 11
// baseline (209.850 us; speedup 1.0000x reference)
//
#include <hip/hip_runtime.h>
#include <stdint.h>

#define B_ 4
#define C_ 256
#define N_ 4096
#define JS 4          // j-splits

typedef unsigned short u16;
typedef unsigned char u8;
typedef long i64;
typedef __attribute__((ext_vector_type(4))) float f32x4;
typedef __attribute__((ext_vector_type(16))) float f32x16;
typedef __attribute__((ext_vector_type(8))) short bf16x8;
typedef __attribute__((ext_vector_type(4))) int i32x4;

__device__ __forceinline__ u16 f2bf(float f) {
    uint32_t u = __float_as_uint(f);
    u += 0x7fffu + ((u >> 16) & 1u);
    return (u16)(u >> 16);
}
__device__ __forceinline__ float bf2f(u16 v) {
    uint32_t u = ((uint32_t)v) << 16;
    return __uint_as_float(u);
}

// ---- fp8 e4m3 pack: two floats into low/high 16 bits of a dword ----
#if defined(__has_builtin)
#if __has_builtin(__builtin_amdgcn_cvt_pk_fp8_f32)
#define HAVE_CVTFP8 1
#endif
#endif

#ifdef HAVE_CVTFP8
template <bool HI>
__device__ __forceinline__ uint32_t pk2fp8(float a, float b, uint32_t old) {
    return (uint32_t)__builtin_amdgcn_cvt_pk_fp8_f32(a, b, (int)old, HI);
}
#else
__device__ __forceinline__ uint32_t fp8_1(float x) {
    uint32_t u = __float_as_uint(x);
    uint32_t s = (u >> 24) & 0x80u;
    float ax = fabsf(x);
    if (ax < 0.0078125f) return s;           // flush < 2^-7
    if (ax > 448.f) return s | 0x7eu;
    uint32_t m = u & 0x7fffffffu;
    m += 0x7ffffu + ((m >> 20) & 1u);        // RNE at 3-bit mantissa
    int e = (int)(m >> 23) - 127;
    if (e < -6) return s;
    return s | ((uint32_t)(e + 7) << 3) | ((m >> 20) & 7u);
}
template <bool HI>
__device__ __forceinline__ uint32_t pk2fp8(float a, float b, uint32_t old) {
    uint32_t lo = fp8_1(a) | (fp8_1(b) << 8);
    return HI ? ((old & 0xffffu) | (lo << 16)) : ((old & 0xffff0000u) | lo);
}
#endif

#if defined(__has_builtin)
#if __has_builtin(__builtin_amdgcn_global_load_lds)
#define HAVE_GLL 1
#endif
#endif

#ifdef HAVE_GLL
__device__ __forceinline__ void g2l16(const u16* g, u16* lbase, int lane) {
    (void)lane;
    __builtin_amdgcn_global_load_lds(
        (__attribute__((address_space(1))) void*)(uintptr_t)g,
        (__attribute__((address_space(3))) void*)lbase, 16, 0, 0);
}
#else
__device__ __forceinline__ void g2l16(const u16* g, u16* lbase, int lane) {
    *(i32x4*)(lbase + lane * 8) = *(const i32x4*)g;
}
#endif

// ---------------- Stage 0: W fp32 -> bf16 ----------------
__global__ __launch_bounds__(256) void wconv_kernel(
    const float* __restrict__ Wq, const float* __restrict__ Wk,
    const float* __restrict__ Wv, u16* __restrict__ Wb) {
    int id = blockIdx.x * 256 + threadIdx.x;
    const float* src = (id < 65536) ? Wq : ((id < 131072) ? Wk : Wv);
    Wb[id] = f2bf(src[id & 65535]);
}

// ---------------- Stage 1: QKV projection, LDS-staged coalesced stores ----------------
// Qt: [B][N][C] bf16 linear. Kt: [B][N][C] bf16, 16B-chunk swizzle chunk^(n&31).
// Vt8: [B][C][N] fp8 e4m3, per-64-tile 8B-chunk swizzle chunk^(o&7).
#define OSS 264
#define VSS 40
__global__ __launch_bounds__(256, 2) void qkv_kernel(
    const float* __restrict__ x, const u16* __restrict__ Wb,
    const float* __restrict__ bq, const float* __restrict__ bk,
    const float* __restrict__ bv,
    u16* __restrict__ Qt, u16* __restrict__ Kt, u8* __restrict__ Vt8) {
    __shared__ __align__(16) u16 smem[256 * VSS];

    int blk = blockIdx.x;
    int n0  = (blk & 127) << 5;
    int b   = blk >> 7;
    int tid = threadIdx.x;
    int lane = tid & 63;
    int w = tid >> 6;
    int l31 = lane & 31;
    int h = lane >> 5;

    {   // stage xT
        int c0 = tid >> 3;
        int nq = (tid & 7) << 2;
        const float* xb = x + ((size_t)b * C_ + c0) * N_ + n0 + nq;
        #pragma unroll
        for (int p = 0; p < 8; ++p) {
            f32x4 v = *(const f32x4*)(xb + (size_t)32 * N_ * p);
            int cc = c0 + 32 * p;
            smem[(nq + 0) * OSS + cc] = f2bf(v[0]);
            smem[(nq + 1) * OSS + cc] = f2bf(v[1]);
            smem[(nq + 2) * OSS + cc] = f2bf(v[2]);
            smem[(nq + 3) * OSS + cc] = f2bf(v[3]);
        }
    }
    __syncthreads();

    bf16x8 xf[16];
    #pragma unroll
    for (int ks = 0; ks < 16; ++ks)
        xf[ks] = *(const bf16x8*)(&smem[l31 * OSS + 16 * ks + 8 * h]);
    __syncthreads();

    // ---- Q and K ----
    #pragma unroll
    for (int mat = 0; mat < 2; ++mat) {
        const u16* W = Wb + mat * 65536;
        const float* bias = mat ? bk : bq;
        u16* dst = mat ? Kt : Qt;
        f32x16 acc0, acc1;
        #pragma unroll
        for (int r = 0; r < 16; ++r) { acc0[r] = 0.f; acc1[r] = 0.f; }
        const u16* wr0 = W + (size_t)(64 * w + l31) * 256 + 8 * h;
        const u16* wr1 = W + (size_t)(64 * w + 32 + l31) * 256 + 8 * h;
        #pragma unroll
        for (int ks = 0; ks < 16; ++ks) {
            bf16x8 wf0 = *(const bf16x8*)(wr0 + 16 * ks);
            bf16x8 wf1 = *(const bf16x8*)(wr1 + 16 * ks);
            acc0 = __builtin_amdgcn_mfma_f32_32x32x16_bf16(xf[ks], wf0, acc0, 0, 0, 0);
            acc1 = __builtin_amdgcn_mfma_f32_32x32x16_bf16(xf[ks], wf1, acc1, 0, 0, 0);
        }
        #pragma unroll
        for (int ot = 0; ot < 2; ++ot) {
            const f32x16& a = ot ? acc1 : acc0;
            int c = 64 * w + 32 * ot + l31;
            float bo = bias[c];
            #pragma unroll
            for (int g = 0; g < 4; ++g)
                #pragma unroll
                for (int r = 0; r < 4; ++r)
                    smem[(8 * g + 4 * h + r) * OSS + c] = f2bf(a[4 * g + r] + bo);
        }
        __syncthreads();
        #pragma unroll
        for (int p = 0; p < 4; ++p) {
            int row = 8 * p + (tid >> 5);
            int chunk = tid & 31;
            int cswz = mat ? (chunk ^ row) : chunk;
            i32x4 v = *(const i32x4*)(smem + row * OSS + chunk * 8);
            *(i32x4*)(dst + ((size_t)b * N_ + n0 + row) * C_ + cswz * 8) = v;
        }
        __syncthreads();
    }

    // ---- V (fp8 output) ----
    {
        const u16* W = Wb + 2 * 65536;
        f32x16 acc0, acc1;
        #pragma unroll
        for (int r = 0; r < 16; ++r) { acc0[r] = 0.f; acc1[r] = 0.f; }
        const u16* wr0 = W + (size_t)(64 * w + l31) * 256 + 8 * h;
        const u16* wr1 = W + (size_t)(64 * w + 32 + l31) * 256 + 8 * h;
        #pragma unroll
        for (int ks = 0; ks < 16; ++ks) {
            bf16x8 wf0 = *(const bf16x8*)(wr0 + 16 * ks);
            bf16x8 wf1 = *(const bf16x8*)(wr1 + 16 * ks);
            acc0 = __builtin_amdgcn_mfma_f32_32x32x16_bf16(wf0, xf[ks], acc0, 0, 0, 0);
            acc1 = __builtin_amdgcn_mfma_f32_32x32x16_bf16(wf1, xf[ks], acc1, 0, 0, 0);
        }
        #pragma unroll
        for (int mt = 0; mt < 2; ++mt) {
            const f32x16& a = mt ? acc1 : acc0;
            #pragma unroll
            for (int g = 0; g < 4; ++g)
                #pragma unroll
                for (int r = 0; r < 4; ++r) {
                    int o = 64 * w + 32 * mt + 8 * g + 4 * h + r;
                    smem[o * VSS + l31] = f2bf(a[4 * g + r] + bv[o]);
                }
        }
        __syncthreads();
        int tb = n0 & ~63;
        int hb = (n0 & 32) >> 3;       // 0 or 4
        #pragma unroll
        for (int p = 0; p < 4; ++p) {
            int o = 64 * p + (tid >> 2);
            int chunk = tid & 3;
            int cswz = (hb + chunk) ^ (o & 7);
            const u16* vs = smem + o * VSS + chunk * 8;
            float f0 = bf2f(vs[0]), f1 = bf2f(vs[1]), f2 = bf2f(vs[2]), f3 = bf2f(vs[3]);
            float f4 = bf2f(vs[4]), f5 = bf2f(vs[5]), f6 = bf2f(vs[6]), f7 = bf2f(vs[7]);
            uint32_t d0 = pk2fp8<false>(f0, f1, 0); d0 = pk2fp8<true>(f2, f3, d0);
            uint32_t d1 = pk2fp8<false>(f4, f5, 0); d1 = pk2fp8<true>(f6, f7, d1);
            uint2 st = {d0, d1};
            *(uint2*)(Vt8 + ((size_t)b * C_ + o) * N_ + tb + cswz * 8) = st;
        }
    }
}

// ---------------- Stage 2: flash attention, bf16 QK + fp8 PV, m==0 ----------------
// Grid 512 = 32 i-tiles(128) x 4 b x 4 s. 48KB LDS, 2 blocks/CU.
__device__ __forceinline__ void stage64(const u16* Kb, const u8* Vb8, int j0,
                                        u16* ksd, u8* vsd, int w, int lane) {
    const u16* kg = Kb + (size_t)(j0 + 16 * w) * C_ + lane * 8;
    u16* kdb = ksd + 16 * w * 256;
    #pragma unroll
    for (int rr = 0; rr < 8; ++rr)
        g2l16(kg + rr * 512, kdb + rr * 512, lane);
    // V fp8: wave w c-rows [64w,64w+64): 4 DMA x 1KB (16 rows of 64B)
    const u8* vg = Vb8 + (size_t)(64 * w + (lane >> 2)) * N_ + j0 + (lane & 3) * 16;
    u8* vdb = vsd + 64 * w * 64;
    #pragma unroll
    for (int rr = 0; rr < 4; ++rr)
        g2l16((const u16*)(vg + (size_t)16 * rr * N_), (u16*)(vdb + rr * 1024), lane);
}

__global__ __launch_bounds__(256, 2) void attn_kernel(
    const u16* __restrict__ Qt, const u16* __restrict__ Kt,
    const u8* __restrict__ Vt8, u16* __restrict__ Op,
    float* __restrict__ lArr) {
    __shared__ __align__(16) u16 Ksh[64 * 256];   // 32KB
    __shared__ __align__(16) u8 Vsh8[256 * 64];   // 16KB fp8

    int blk = blockIdx.x;
    int it = blk & 31;
    int b  = (blk >> 5) & 3;
    int s  = blk >> 7;
    int i0 = it << 7;
    int tid = threadIdx.x;
    int lane = tid & 63;
    int w = tid >> 6;
    int l31 = lane & 31;
    int h = lane >> 5;

    bf16x8 qf[16];
    {
        const u16* qrow = Qt + ((size_t)b * N_ + i0 + 32 * w + l31) * C_ + 8 * h;
        #pragma unroll
        for (int ks = 0; ks < 16; ++ks) qf[ks] = *(const bf16x8*)(qrow + 16 * ks);
    }

    f32x16 oacc[8];
    #pragma unroll
    for (int mt = 0; mt < 8; ++mt)
        #pragma unroll
        for (int r = 0; r < 16; ++r) oacc[mt][r] = 0.f;
    float l_run = 0.f;

    const float sconst = 0.0625f * 1.44269504088896340736f;
    const u16* Kb = Kt + (size_t)b * N_ * C_;
    const u8* Vb8 = Vt8 + (size_t)b * C_ * N_;
    int jbase = s * (N_ / JS);
    const int T = N_ / (64 * JS);

    stage64(Kb, Vb8, jbase, Ksh, Vsh8, w, lane);
    __syncthreads();

    for (int jt = 0; jt < T; ++jt) {
        // S^T = K·Q^T (bf16)
        f32x16 st0, st1;
        #pragma unroll
        for (int r = 0; r < 16; ++r) { st0[r] = 0.f; st1[r] = 0.f; }
        #pragma unroll
        for (int ks = 0; ks < 16; ++ks) {
            int kc = ((2 * ks + h) ^ l31) << 3;
            bf16x8 kf0 = *(const bf16x8*)(Ksh + l31 * 256 + kc);
            bf16x8 kf1 = *(const bf16x8*)(Ksh + (32 + l31) * 256 + kc);
            st0 = __builtin_amdgcn_mfma_f32_32x32x16_bf16(kf0, qf[ks], st0, 0, 0, 0);
            st1 = __builtin_amdgcn_mfma_f32_32x32x16_bf16(kf1, qf[ks], st1, 0, 0, 0);
        }

        // softmax numerators (m=0), packed to fp8 quads
        float psum = 0.f;
        uint32_t pd[8];   // u 0..3: st0 g0..3, u 4..7: st1 g0..3; each = 4 fp8 (r0..3)
        #pragma unroll
        for (int u = 0; u < 8; ++u) {
            const f32x16& stv = (u < 4) ? st0 : st1;
            int g = u & 3;
            float p0 = exp2f(stv[4 * g + 0] * sconst);
            float p1 = exp2f(stv[4 * g + 1] * sconst);
            float p2 = exp2f(stv[4 * g + 2] * sconst);
            float p3 = exp2f(stv[4 * g + 3] * sconst);
            psum += (p0 + p1) + (p2 + p3);
            uint32_t t = pk2fp8<false>(p0, p1, 0);
            pd[u] = pk2fp8<true>(p2, p3, t);
        }
        psum += __shfl_xor(psum, 32);
        l_run += psum;

        // O += V·P (fp8): per ks2 exchange one quad with lane^32
        #pragma unroll
        for (int ks2 = 0; ks2 < 4; ++ks2) {
            int qo = 2 * ks2 + h;          // quad kept
            int qs = 2 * ks2 + 1 - h;      // quad sent
            uint32_t recv = (uint32_t)__shfl_xor((int)pd[qs], 32);
            uint32_t d0 = h ? recv : pd[qo];
            uint32_t d1 = h ? pd[qo] : recv;
            i64 pb = (i64)(((uint64_t)d1 << 32) | (uint64_t)d0);
            int vc = ((2 * ks2 + h) ^ (l31 & 7)) << 3;
            #pragma unroll
            for (int mt = 0; mt < 8; ++mt) {
                i64 vv = *(const i64*)(Vsh8 + (32 * mt + l31) * 64 + vc);
                oacc[mt] = __builtin_amdgcn_mfma_f32_32x32x16_fp8_fp8(vv, pb, oacc[mt], 0, 0, 0);
            }
        }

        if (jt + 1 < T) {
            __syncthreads();
            stage64(Kb, Vb8, jbase + (jt + 1) * 64, Ksh, Vsh8, w, lane);
            __syncthreads();
        }
    }

    int i = i0 + 32 * w + l31;
    u16* ob = Op + ((size_t)(s * B_ + b) * C_) * N_ + i;
    #pragma unroll
    for (int mt = 0; mt < 8; ++mt)
        #pragma unroll
        for (int g = 0; g < 4; ++g)
            #pragma unroll
            for (int r = 0; r < 4; ++r) {
                int c = 32 * mt + 8 * g + r + 4 * h;
                ob[(size_t)c * N_] = f2bf(oacc[mt][4 * g + r]);
            }
    if (h == 0) lArr[(size_t)(s * B_ + b) * N_ + i] = l_run;
}

// ---------------- Stage 3: merge splits + residual ----------------
__global__ __launch_bounds__(256) void merge_kernel(
    const float* __restrict__ x, const u16* __restrict__ Op,
    const float* __restrict__ lArr, float* __restrict__ out) {
    int blk = blockIdx.x;
    int b  = blk >> 7;
    int i4 = (blk & 127) * 32 + (threadIdx.x & 7) * 4;
    int cb = threadIdx.x >> 3;

    f32x4 L = {0.f, 0.f, 0.f, 0.f};
    #pragma unroll
    for (int s = 0; s < JS; ++s) {
        f32x4 lv = *(const f32x4*)(lArr + (size_t)(s * B_ + b) * N_ + i4);
        L += lv;
    }
    f32x4 rL;
    #pragma unroll
    for (int k = 0; k < 4; ++k) rL[k] = 1.0f / L[k];

    #pragma unroll
    for (int kk = 0; kk < 8; ++kk) {
        int c = kk * 32 + cb;
        size_t xi = ((size_t)b * C_ + c) * N_ + i4;
        f32x4 acc = {0.f, 0.f, 0.f, 0.f};
        #pragma unroll
        for (int s = 0; s < JS; ++s) {
            ushort4 v = *(const ushort4*)(Op + ((size_t)(s * B_ + b) * C_ + c) * N_ + i4);
            acc[0] += bf2f(v.x);
            acc[1] += bf2f(v.y);
            acc[2] += bf2f(v.z);
            acc[3] += bf2f(v.w);
        }
        f32x4 xv = *(const f32x4*)(x + xi);
        f32x4 ov;
        #pragma unroll
        for (int k = 0; k < 4; ++k) ov[k] = fmaf(acc[k], rL[k], xv[k]);
        *(f32x4*)(out + xi) = ov;
    }
}

extern "C" void kernel_launch(void* const* d_in, const int* in_sizes, int n_in,
                              void* d_out, int out_size, void* d_ws, size_t ws_size,
                              hipStream_t stream) {
    const float* x  = (const float*)d_in[0];
    const float* Wq = (const float*)d_in[1];
    const float* bq = (const float*)d_in[2];
    const float* Wk = (const float*)d_in[3];
    const float* bk = (const float*)d_in[4];
    const float* Wv = (const float*)d_in[5];
    const float* bv = (const float*)d_in[6];
    float* out = (float*)d_out;

    u16* Wb = (u16*)d_ws;
    u16* Qt = Wb + 3 * 65536;                     // [B][N][C] bf16 linear
    u16* Kt = Qt + (size_t)B_ * N_ * C_;          // [B][N][C] bf16 swizzled
    u8*  Vt8 = (u8*)(Kt + (size_t)B_ * N_ * C_);  // [B][C][N] fp8 swizzled
    u16* Op = (u16*)(Vt8 + (size_t)B_ * C_ * N_); // [JS][B][C][N] bf16
    float* lArr = (float*)(Op + (size_t)JS * B_ * C_ * N_);

    wconv_kernel<<<768, 256, 0, stream>>>(Wq, Wk, Wv, Wb);
    qkv_kernel<<<512, 256, 0, stream>>>(x, Wb, bq, bk, bv, Qt, Kt, Vt8);
    attn_kernel<<<512, 256, 0, stream>>>(Qt, Kt, Vt8, Op, lArr);
    merge_kernel<<<512, 256, 0, stream>>>(x, Op, lArr, out);
}